// Round 9
// baseline (338.759 us; speedup 1.0000x reference)
//
#include <hip/hip_runtime.h>
#include <cstdint>
#include <cstddef>

// SummaryAdapter fused kernel for MI355X (gfx950), v9: v8 with LDS squeezed
// 24.8KB -> 12.8KB via lifetime-chained buffer aliasing + 4KB staging chunks
// + double-buffered P5 resid tile (1 barrier/chunk). 8 blocks/CU, 32 waves =
// 100% occupancy. All global h touches stay single-row coalesced.
// L=8 B=2 S=4096 D=2048 N=128 Ds=1024 Da=64.
//
// LDS map (12800 B), lifetime-aliased:
//   P1: stage buf0 @0..4096, buf1 @4096..8192 (chunk c uses buf 1-(c&1))
//   qsc f32[16] stride 66  @4096  (written end-P1; safe: last chunk reads buf0)
//   scb f32[16] stride 128 @0     (P2 write after extra sync; P3 read)
//   Pb  u16[16] stride 136 @8192  (P3 write, P4 read)
//   aob f32[16] stride 66  @0     (P4 write, P5 bfrag read)
//   resb u16[16] stride 132, dbuf @4352 / @8576 (P5, 1 sync per chunk)
//
// Workspace layout (bytes):          off      size
//   KF  frag bf16                      0    262144
//   VF  frag bf16                 262144    262144
//   WqF frag bf16                 524288   2097152
//   WoF frag bf16                2621440   2097152
// Requires ws_size >= 4718592.

typedef __attribute__((ext_vector_type(8))) short short8;   // 8 x bf16
typedef __attribute__((ext_vector_type(4))) float f32x4;
typedef __attribute__((ext_vector_type(4))) unsigned short u16x4;

#define MFMA16(a, b, c) __builtin_amdgcn_mfma_f32_16x16x32_bf16((a), (b), (c), 0, 0, 0)

__device__ __forceinline__ unsigned short f2bf(float f) {
  unsigned int x = __builtin_bit_cast(unsigned int, f);
  x += 0x7fffu + ((x >> 16) & 1u);        // RNE
  return (unsigned short)(x >> 16);
}
__device__ __forceinline__ float bf2f(unsigned short u) {
  return __builtin_bit_cast(float, (unsigned int)u << 16);
}
__device__ __forceinline__ short8 cvt8v(f32x4 a, f32x4 b) {
  short8 r;
  r[0] = (short)f2bf(a[0]); r[1] = (short)f2bf(a[1]);
  r[2] = (short)f2bf(a[2]); r[3] = (short)f2bf(a[3]);
  r[4] = (short)f2bf(b[0]); r[5] = (short)f2bf(b[1]);
  r[6] = (short)f2bf(b[2]); r[7] = (short)f2bf(b[3]);
  return r;
}
__device__ __forceinline__ short8 ld_cvt8(const float* p) {
  f32x4 v0 = *(const f32x4*)p, v1 = *(const f32x4*)(p + 4);
  return cvt8v(v0, v1);
}
__device__ __forceinline__ u16x4 pack4(f32x4 v) {
  u16x4 r;
  r[0] = f2bf(v[0]); r[1] = f2bf(v[1]); r[2] = f2bf(v[2]); r[3] = f2bf(v[3]);
  return r;
}

// ---------------- pre 1: K = bank@Wk^T, V = bank@Wv^T via MFMA -------------
__global__ __launch_bounds__(64)
void pre_kv_kernel(const float* __restrict__ bank,
                   const float* __restrict__ Wk,
                   const float* __restrict__ Wv,
                   unsigned short* __restrict__ KF, unsigned short* __restrict__ VF) {
  int bid = blockIdx.x;
  int at = bid & 3, nt = (bid >> 2) & 7, kv = (bid >> 5) & 1;
  int b = (bid >> 6) & 1, l = bid >> 7;
  int lane = threadIdx.x & 63;
  int lo = lane & 15, hi = lane >> 4;
  const float* W  = (kv ? Wv : Wk) + (size_t)l * 65536;
  const float* bk = bank + (size_t)b * 131072;
  int lbq = l * 2 + b;
  f32x4 acc = (f32x4){0.f, 0.f, 0.f, 0.f};
  for (int ks = 0; ks < 32; ++ks) {
    short8 A = ld_cvt8(bk + (nt * 16 + lo) * 1024 + ks * 32 + hi * 8);
    short8 B = ld_cvt8(W + (at * 16 + lo) * 1024 + ks * 32 + hi * 8);
    acc = MFMA16(A, B, acc);
  }
  for (int r = 0; r < 4; ++r) {
    int n = nt * 16 + hi * 4 + r;
    int a = at * 16 + lo;
    unsigned short v = f2bf(acc[r]);
    if (kv == 0) {
      int idx = ((lbq * 8 + (n >> 4)) * 2 + (a >> 5)) * 512 +
                (((a >> 3) & 3) * 16 + (n & 15)) * 8 + (a & 7);
      KF[idx] = v;
    } else {
      int idx = ((lbq * 4 + (a >> 4)) * 4 + (n >> 5)) * 512 +
                (((n >> 3) & 3) * 16 + (a & 15)) * 8 + (n & 7);
      VF[idx] = v;
    }
  }
}

// ---------------- pre 2: Wq/Wo -> bf16 fragment layout ---------------------
__global__ void pre_frag_kernel(const float* __restrict__ Wq, const float* __restrict__ Wo,
                                unsigned short* __restrict__ WqF, unsigned short* __restrict__ WoF) {
  int idx = blockIdx.x * 256 + threadIdx.x;        // 262144 threads
  if (idx < 131072) {
    int t = idx;
    int lane = t & 63, ks = (t >> 6) & 63, at = (t >> 12) & 3, l = t >> 14;
    int a = at * 16 + (lane & 15), d = ks * 32 + (lane >> 4) * 8;
    *(short8*)(WqF + (size_t)t * 8) = ld_cvt8(Wq + ((size_t)(l * 64 + a)) * 2048 + d);
  } else {
    int t = idx - 131072;
    int lane = t & 63, ks = (t >> 6) & 1, dt = (t >> 7) & 127, l = t >> 14;
    int d = dt * 16 + (lane & 15), a = ks * 32 + (lane >> 4) * 8;
    *(short8*)(WoF + (size_t)t * 8) = ld_cvt8(Wo + ((size_t)(l * 2048 + d)) * 64 + a);
  }
}

// ---------------- main fused kernel ----------------------------------------
__global__ __launch_bounds__(256, 8)
void adapter_main(const float* __restrict__ hidden,
                  const unsigned short* __restrict__ KF, const unsigned short* __restrict__ VF,
                  const unsigned short* __restrict__ WqF, const unsigned short* __restrict__ WoF,
                  const float* __restrict__ gates, float* __restrict__ out) {
  __shared__ __align__(16) char smem[12800];
  float* qsc = (float*)(smem + 4096);               // stride 66 f32
  float* scb = (float*)smem;                        // stride 128 f32
  unsigned short* Pb = (unsigned short*)(smem + 8192); // stride 136 u16
  float* aob = (float*)smem;                        // stride 66 f32

  // XCD-bijective swizzle (4096 % 8 == 0): XCD x gets 512 tiles = layer x.
  int bid0 = blockIdx.x;
  int bid = (bid0 & 7) * 512 + (bid0 >> 3);
  int st = bid & 255, b = (bid >> 8) & 1, l = bid >> 9;
  int tid = threadIdx.x, wave = tid >> 6, lane = tid & 63;
  int lo = lane & 15, hi = lane >> 4;
  int l32 = lane & 31, lh = lane >> 5;               // staging lane split
  size_t hbase = ((size_t)(l * 2 + b) * 4096 + st * 16) * 2048;
  const char* hby = (const char*)(hidden + hbase);
  float gate = 1.0f / (1.0f + __expf(-gates[l]));
  int lb = l * 2 + b;
  int at = wave;

  // ---- Phase 1: Q = h @ Wq^T; 16 chunks of 16 rows x 512B, dbuf staging ----
  // Load: s2 in {0,1}: rows (s2*4+wave)*2 + lh; 64 lanes x 16B, 2 rows/instr.
  f32x4 sreg[2];
  f32x4 qacc = (f32x4){0.f, 0.f, 0.f, 0.f};
  {
    const unsigned short* wqb = WqF + ((size_t)(l * 4 + at) * 64) * 512 + lane * 8;

#define LOADC(c)                                                             \
    _Pragma("unroll")                                                        \
    for (int s2 = 0; s2 < 2; ++s2) {                                         \
      int row = (s2 * 4 + wave) * 2 + lh;                                    \
      sreg[s2] = *(const f32x4*)(hby + (size_t)row * 8192 + (size_t)(c) * 512 + l32 * 16); \
    }
#define WRITEC(c)                                                            \
    _Pragma("unroll")                                                        \
    for (int s2 = 0; s2 < 2; ++s2) {                                         \
      int row = (s2 * 4 + wave) * 2 + lh;                                    \
      u16x4 pk = pack4(sreg[s2]);                                            \
      *(u16x4*)(smem + (1 - ((c) & 1)) * 4096 + row * 256 + ((l32 * 8) ^ ((row & 7) << 4))) = pk; \
    }

    LOADC(0); WRITEC(0);
    #pragma unroll 1
    for (int c = 0; c < 16; ++c) {
      __syncthreads();                             // chunk c staged
      if (c < 15) LOADC(c + 1);
      const char* rb = smem + (1 - (c & 1)) * 4096 + lo * 256;
      int sw = (lo & 7) << 4;
      #pragma unroll
      for (int ks = 0; ks < 4; ++ks) {
        short8 A = *(const short8*)(rb + ((ks * 64 + hi * 16) ^ sw));
        short8 B = *(const short8*)(wqb + (size_t)(c * 4 + ks) * 512);
        qacc = MFMA16(A, B, qacc);
      }
      if (c < 15) WRITEC(c + 1);
    }
#undef LOADC
#undef WRITEC
  }

  // last chunk read buf0 @[0,4096); Q-write targets @[4096,8320) = safe.
  #pragma unroll
  for (int r = 0; r < 4; ++r)                      // fold 1/sqrt(64)
    qsc[(hi * 4 + r) * 66 + at * 16 + lo] = qacc[r] * 0.125f;
  __syncthreads();

  // ---- Phase 2: afrag from Q; sync; scores = Q @ K^T -> scb ----
  {
    short8 afrag[2];
    #pragma unroll
    for (int ks = 0; ks < 2; ++ks) {
      const float* qp = qsc + lo * 66 + ks * 32 + hi * 8;
      afrag[ks] = cvt8v(*(const f32x4*)qp, *(const f32x4*)(qp + 4));
    }
    __syncthreads();                               // all qsc reads before scb writes
    #pragma unroll
    for (int i = 0; i < 2; ++i) {
      int nt = wave * 2 + i;
      f32x4 acc = (f32x4){0.f, 0.f, 0.f, 0.f};
      const unsigned short* kf = KF + ((size_t)(lb * 8 + nt) * 2) * 512 + lane * 8;
      acc = MFMA16(afrag[0], *(const short8*)(kf), acc);
      acc = MFMA16(afrag[1], *(const short8*)(kf + 512), acc);
      #pragma unroll
      for (int r = 0; r < 4; ++r)
        scb[(hi * 4 + r) * 128 + nt * 16 + lo] = acc[r];
    }
  }
  __syncthreads();

  // ---- Phase 3: softmax over N=128 (16 lanes per row) -> Pb bf16 ----
  {
    int row = wave * 4 + hi;
    const float* sp = scb + row * 128 + lo * 8;
    f32x4 v0 = *(const f32x4*)sp, v1 = *(const f32x4*)(sp + 4);
    float m = fmaxf(fmaxf(fmaxf(v0[0], v0[1]), fmaxf(v0[2], v0[3])),
                    fmaxf(fmaxf(v1[0], v1[1]), fmaxf(v1[2], v1[3])));
    m = fmaxf(m, __shfl_xor(m, 1)); m = fmaxf(m, __shfl_xor(m, 2));
    m = fmaxf(m, __shfl_xor(m, 4)); m = fmaxf(m, __shfl_xor(m, 8));
    f32x4 e0, e1; float s = 0.f;
    #pragma unroll
    for (int j = 0; j < 4; ++j) { e0[j] = __expf(v0[j] - m); s += e0[j]; }
    #pragma unroll
    for (int j = 0; j < 4; ++j) { e1[j] = __expf(v1[j] - m); s += e1[j]; }
    s += __shfl_xor(s, 1); s += __shfl_xor(s, 2);
    s += __shfl_xor(s, 4); s += __shfl_xor(s, 8);
    float inv = 1.0f / s;
    #pragma unroll
    for (int j = 0; j < 4; ++j) { e0[j] *= inv; e1[j] *= inv; }
    *(short8*)((char*)Pb + row * 272 + lo * 16) = cvt8v(e0, e1);
  }
  __syncthreads();

  // ---- Phase 4: attn_out = P @ V -> aob (aliases dead scb) ----
  {
    short8 pfrag[4];
    #pragma unroll
    for (int ks = 0; ks < 4; ++ks)
      pfrag[ks] = *(const short8*)((const char*)Pb + lo * 272 + ks * 64 + hi * 16);
    const unsigned short* vf = VF + ((size_t)(lb * 4 + at) * 4) * 512 + lane * 8;
    f32x4 a = (f32x4){0.f, 0.f, 0.f, 0.f};
    #pragma unroll
    for (int ks = 0; ks < 4; ++ks)
      a = MFMA16(pfrag[ks], *(const short8*)(vf + (size_t)ks * 512), a);
    #pragma unroll
    for (int r = 0; r < 4; ++r)
      aob[(hi * 4 + r) * 66 + at * 16 + lo] = a[r];
  }
  __syncthreads();

  // ---- Phase 5: 16 d-chunks of 128 cols, dbuf resid tile, 1 sync/chunk ----
  {
    short8 bfrag[2];
    #pragma unroll
    for (int ks = 0; ks < 2; ++ks) {
      const float* ap2 = aob + lo * 66 + ks * 32 + hi * 8;
      bfrag[ks] = cvt8v(*(const f32x4*)ap2, *(const f32x4*)(ap2 + 4));
    }
    float* ob = out + hbase;
    #pragma unroll 1
    for (int c = 0; c < 16; ++c) {
      char* resb = smem + 4352 + (c & 1) * 4224;   // u16 [16][132]
      #pragma unroll
      for (int j = 0; j < 2; ++j) {
        int dtl = wave * 2 + j;                    // 0..7 within chunk
        int dt = c * 8 + dtl;
        const unsigned short* wo = WoF + ((size_t)(l * 128 + dt) * 2) * 512 + lane * 8;
        short8 A0 = *(const short8*)(wo);
        short8 A1 = *(const short8*)(wo + 512);
        f32x4 acc = (f32x4){0.f, 0.f, 0.f, 0.f};
        acc = MFMA16(A0, bfrag[0], acc);
        acc = MFMA16(A1, bfrag[1], acc);
        // resid^T frag: s = lo, d_local = dtl*16 + hi*4 + r
        *(u16x4*)(resb + lo * 264 + dtl * 32 + hi * 8) = pack4(acc);
      }
      __syncthreads();                             // resid chunk c ready
      #pragma unroll
      for (int i2 = 0; i2 < 2; ++i2) {
        int row = (i2 * 4 + wave) * 2 + lh;        // 2 rows per instr
        size_t off = (size_t)row * 8192 + (size_t)c * 512 + l32 * 16;
        f32x4 hv = *(const f32x4*)(hby + off);     // L2/L3 hit (read in P1)
        u16x4 rv = *(const u16x4*)(resb + row * 264 + l32 * 8);
        f32x4 o;
        #pragma unroll
        for (int r = 0; r < 4; ++r) o[r] = hv[r] + gate * bf2f(rv[r]);
        __builtin_nontemporal_store(o, (f32x4*)((char*)ob + off));
      }
      // next chunk writes the other resb buffer; reads of this one are
      // protected by the sync inside the next iteration.
    }
  }
}

extern "C" void kernel_launch(void* const* d_in, const int* in_sizes, int n_in,
                              void* d_out, int out_size, void* d_ws, size_t ws_size,
                              hipStream_t stream) {
  const float* hidden = (const float*)d_in[0];
  const float* bank   = (const float*)d_in[1];
  const float* Wq     = (const float*)d_in[2];
  const float* Wk     = (const float*)d_in[3];
  const float* Wv     = (const float*)d_in[4];
  const float* Wo     = (const float*)d_in[5];
  const float* gates  = (const float*)d_in[6];
  float* out = (float*)d_out;

  char* ws = (char*)d_ws;
  unsigned short* KF  = (unsigned short*)(ws);
  unsigned short* VF  = (unsigned short*)(ws + 262144);
  unsigned short* WqF = (unsigned short*)(ws + 524288);
  unsigned short* WoF = (unsigned short*)(ws + 2621440);

  pre_kv_kernel<<<1024, 64, 0, stream>>>(bank, Wk, Wv, KF, VF);
  pre_frag_kernel<<<1024, 256, 0, stream>>>(Wq, Wo, WqF, WoF);
  adapter_main<<<4096, 256, 0, stream>>>(hidden, KF, VF, WqF, WoF, gates, out);
}